// Round 6
// baseline (171.452 us; speedup 1.0000x reference)
//
#include <hip/hip_runtime.h>

#define NRBF 20
#define FOUT 16
#define NA 768
#define NB 4
#define TSTR 17                 // padded LDS tile stride (17 coprime 32 -> 2-way max, free)
#define TSZ (64 * TSTR)

// Round-6 design:
//  - wave w owns f-quad 4w..4w+3  -> W is wave-uniform -> pinned to SGPRs via
//    readfirstlane (frees the 80-VGPR wk cache that capped occupancy at 2 waves/SIMD)
//  - lane l owns m = j*64 + l
//  - acc written to padded LDS tile, then cooperative lane-consecutive float4
//    copy-out (keeps the round-4 coalesced-store win despite the wave-f mapping)
//  - RBF geometric recurrence: r0=e^{-10d^2}, t1=e^{2d-0.1}, r*=t, t*=e^{-0.2}

__device__ __forceinline__ float rfl(float x) {
    return __int_as_float(__builtin_amdgcn_readfirstlane(__float_as_int(x)));
}

__global__ __launch_bounds__(256) void cfconv_kernel(
    const float* __restrict__ coords,  // [NB, NA, 3]
    const float* __restrict__ Ww,      // [FOUT, NRBF]
    const float* __restrict__ Wb,      // [FOUT]
    float* __restrict__ out)           // [NB, NA, NA, FOUT]
{
    __shared__ float Wt[NRBF * FOUT];   // transposed: Wt[k*16 + f]
    __shared__ float cm[NA * 3];
    __shared__ float tile[2 * TSZ];     // double-buffered 64m x 16f staging

    const int tid  = threadIdx.x;
    const int w    = tid >> 6;          // wave id == f-quad
    const int lane = tid & 63;          // m within 64-m tile
    const int n    = blockIdx.x;
    const int b    = blockIdx.y;

    for (int i = tid; i < NRBF * FOUT; i += 256) {
        int k = i >> 4, f = i & 15;
        Wt[i] = Ww[f * NRBF + k];
    }
    const float* cb = coords + (size_t)b * NA * 3;
    for (int i = tid; i < NA * 3; i += 256) cm[i] = cb[i];
    __syncthreads();

    // pin this wave's 80 W floats into SGPRs (address is wave-uniform)
    float wx[NRBF], wy[NRBF], wz[NRBF], wv[NRBF];
    #pragma unroll
    for (int k = 0; k < NRBF; ++k) {
        const float* p = &Wt[k * FOUT + 4 * w];
        wx[k] = rfl(p[0]); wy[k] = rfl(p[1]);
        wz[k] = rfl(p[2]); wv[k] = rfl(p[3]);
    }
    const float bx = rfl(Wb[4 * w + 0]), by = rfl(Wb[4 * w + 1]),
                bz = rfl(Wb[4 * w + 2]), bw = rfl(Wb[4 * w + 3]);

    const float xn = cb[n * 3 + 0];
    const float yn = cb[n * 3 + 1];
    const float zn = cb[n * 3 + 2];
    const float u  = 0.81873075308f;    // e^{-0.2}

    float* orow = out + ((size_t)b * NA + n) * NA * FOUT;

    const int q  = tid >> 2;            // copy-out: m-local
    const int fr = 4 * (tid & 3);       // copy-out: f base

    #pragma unroll 1
    for (int j = 0; j < NA / 64; ++j) {
        float* tb = &tile[(j & 1) * TSZ];

        const int m = j * 64 + lane;
        const float dx = xn - cm[m * 3 + 0];
        const float dy = yn - cm[m * 3 + 1];
        const float dz = zn - cm[m * 3 + 2];
        const float d2 = dx * dx + dy * dy + dz * dz;
        const float d  = sqrtf(d2);

        float r = __expf(-10.0f * d2);      // r_0
        float t = __expf(2.0f * d - 0.1f);  // t_1

        float ax = fmaf(r, wx[0], bx);
        float ay = fmaf(r, wy[0], by);
        float az = fmaf(r, wz[0], bz);
        float aw = fmaf(r, wv[0], bw);
        #pragma unroll
        for (int k = 1; k < NRBF; ++k) {
            r *= t;
            t *= u;
            ax = fmaf(r, wx[k], ax);
            ay = fmaf(r, wy[k], ay);
            az = fmaf(r, wz[k], az);
            aw = fmaf(r, wv[k], aw);
        }

        float* tw = tb + lane * TSTR + 4 * w;   // banks 17l+4w: 2-way, free
        tw[0] = ax; tw[1] = ay; tw[2] = az; tw[3] = aw;
        __syncthreads();

        const float* tr = tb + q * TSTR + fr;   // banks 17q+4r: 2-way, free
        float4 v = make_float4(tr[0], tr[1], tr[2], tr[3]);
        *reinterpret_cast<float4*>(orow + (size_t)j * 64 * FOUT + tid * 4) = v;
        // double buffer: next j writes the other tile; sync at j+1 orders the
        // j-reads before the j+2 rewrites of this buffer
    }
}

extern "C" void kernel_launch(void* const* d_in, const int* in_sizes, int n_in,
                              void* d_out, int out_size, void* d_ws, size_t ws_size,
                              hipStream_t stream) {
    const float* coords = (const float*)d_in[0];
    const float* Ww     = (const float*)d_in[1];
    const float* Wb     = (const float*)d_in[2];
    float* out          = (float*)d_out;

    dim3 grid(NA, NB);   // (n, b)
    cfconv_kernel<<<grid, 256, 0, stream>>>(coords, Ww, Wb, out);
}